// Round 5
// baseline (258.074 us; speedup 1.0000x reference)
//
#include <hip/hip_runtime.h>
#include <hip/hip_bf16.h>

// ConvNeXtLoss: fused attention-BCE + dice + reverse-dice over (16,4,512,512).
// Single kernel: per-(b,c)-plane partial sums + last-block finalize.
//
// R5 changes vs R4 (tripwire fail: counter started at poison 0xAA..AA ==
// 682 mod 2048, so the (old&2047)==2047 trigger fired after only 1366
// blocks of the CURRENT call; re-poisoned ws partials were read as poison):
//  - hipMemsetAsync(counter, 0, 4, stream) before the kernel (memset nodes
//    are graph-capturable). Trigger is now old == NBLOCKS-1: fires only
//    after ALL 2048 blocks have released their partials.
//  - rest identical to R4: inline-asm global_load_dwordx4 into named regs,
//    4-pair-deep software pipeline with counted vmcnt + sched_barrier(0).

typedef float f32x4 __attribute__((ext_vector_type(4)));
typedef int   i32x4 __attribute__((ext_vector_type(4)));

#define B_DIM 16
#define C_DIM 4
#define HW 262144            // 512*512 plane
#define NPLANES 64           // B*C
#define K_CHUNKS 32          // blocks per plane
#define CHUNK (HW / K_CHUNKS)  // 8192 elements per block
#define NBLOCKS (NPLANES * K_CHUNKS)  // 2048
#define NSUMS 6

__global__ __launch_bounds__(256, 4) void loss_main(
    const float* __restrict__ pred, const int* __restrict__ label,
    float* __restrict__ ws, unsigned* __restrict__ counter,
    float* __restrict__ out, int fuse) {
  const int block = blockIdx.x;          // 0..2047
  const int plane = block >> 5;          // /K_CHUNKS
  const int chunk = block & (K_CHUNKS - 1);
  const long base = (long)plane * HW + (long)chunk * CHUNK;
  const f32x4* p4 = (const f32x4*)(pred + base);
  const i32x4* t4 = (const i32x4*)(label + base);
  const int tid = threadIdx.x;

  f32x4 P0, P1, P2, P3, P4, P5, P6, P7;
  i32x4 T0, T1, T2, T3, T4, T5, T6, T7;

#define ISSUE(K)                                                        \
  asm volatile("global_load_dwordx4 %0, %1, off"                        \
               : "=v"(P##K) : "v"(p4 + tid + K * 256));                 \
  asm volatile("global_load_dwordx4 %0, %1, off"                       \
               : "=v"(T##K) : "v"(t4 + tid + K * 256));

  float s_pt = 0.f, s_pp = 0.f, s_p = 0.f;
  float nsum_t = 0.f;   // sum over ALL elems of  Bw * (-L)
  float nsum_1 = 0.f;   // sum over t==1 elems of Bw * (-L)
  int   s_ti = 0;       // integer count of positives

#define PROC(PK, TK)                                                    \
  _Pragma("unroll")                                                     \
  for (int j = 0; j < 4; ++j) {                                         \
    float pv = PK[j];                                                   \
    float tf = (float)TK[j];                 /* labels exactly 0/1 */   \
    float u   = __builtin_fmaf(tf, -2.0f, 1.0f);   /* 1-2t */           \
    float arg = __builtin_fmaf(pv, u, tf);         /* t?p:1-p */        \
    float x   = 1.0f - arg;                        /* t?1-p:p */        \
    float r   = __builtin_amdgcn_sqrtf(x);                              \
    float Bw  = __builtin_amdgcn_exp2f(3.0f * r);  /* 8^sqrt(x) */      \
    float lg  = __builtin_amdgcn_logf(arg);        /* log2 */           \
    float L   = fmaxf(0.69314718056f * lg, -100.0f);                    \
    float c   = Bw * (-L);                                              \
    nsum_t += c;                                                        \
    nsum_1  = __builtin_fmaf(tf, c, nsum_1);                            \
    s_pt    = __builtin_fmaf(tf, pv, s_pt);                             \
    s_pp    = __builtin_fmaf(pv, pv, s_pp);                             \
    s_p    += pv;                                                       \
    s_ti   += TK[j];                                                    \
  }

#define STEP(K, NW)                                                     \
  asm volatile("s_waitcnt vmcnt(" #NW ")" ::: "memory");                \
  __builtin_amdgcn_sched_barrier(0);                                    \
  PROC(P##K, T##K)

  // prologue: 4 pairs (8 loads) in flight
  ISSUE(0) ISSUE(1) ISSUE(2) ISSUE(3)
  // steady state: wait oldest pair, compute it, issue next pair
  STEP(0, 6) ISSUE(4)
  STEP(1, 6) ISSUE(5)
  STEP(2, 6) ISSUE(6)
  STEP(3, 6) ISSUE(7)
  // drain
  STEP(4, 6)
  STEP(5, 4)
  STEP(6, 2)
  STEP(7, 0)

#undef ISSUE
#undef PROC
#undef STEP

  float s_t = (float)s_ti;

  // wave reduce (64 lanes), then cross-wave via LDS
  float vals[NSUMS] = {s_pt, s_pp, s_t, s_p, nsum_1, nsum_t};
  __shared__ float lds[4][NSUMS];
  __shared__ unsigned lflag;
#pragma unroll
  for (int q = 0; q < NSUMS; ++q) {
    float v = vals[q];
#pragma unroll
    for (int off = 32; off; off >>= 1) v += __shfl_down(v, off);
    vals[q] = v;
  }
  const int wave = tid >> 6;
  if ((tid & 63) == 0) {
#pragma unroll
    for (int q = 0; q < NSUMS; ++q) lds[wave][q] = vals[q];
  }
  __syncthreads();
  if (tid < NSUMS) {
    float v = lds[0][tid] + lds[1][tid] + lds[2][tid] + lds[3][tid];
    ws[block * NSUMS + tid] = v;
  }

  if (!fuse) return;

  // ---- last-block finalize (counter memset to 0 each call) ----
  __syncthreads();        // partial writes issued by whole block
  __threadfence();        // device-scope release
  if (tid == 0) {
    unsigned old = atomicAdd(counter, 1u);
    lflag = (old == (unsigned)(NBLOCKS - 1)) ? 1u : 0u;
  }
  __syncthreads();
  if (lflag == 0u) return;
  __threadfence();        // acquire: make all blocks' partials visible

  if (tid < 64) {
    const int p = tid;    // plane index; b = p>>2, c = p&3
    float s[NSUMS] = {0.f, 0.f, 0.f, 0.f, 0.f, 0.f};
    for (int k = 0; k < K_CHUNKS; ++k) {
      const float* w = ws + (p * K_CHUNKS + k) * NSUMS;
#pragma unroll
      for (int q = 0; q < NSUMS; ++q) s[q] += w[q];
    }
    const float s_pt2 = s[0], s_pp2 = s[1], s_t2 = s[2], s_p2 = s[3];
    const float sum1 = s[4];         // t==1 part
    const float sum2 = s[5] - s[4];  // t==0 part
    const float N = (float)HW;
    const float SM = 1e-6f;

    float dice = 1.0f - (2.0f * s_pt2 + SM) / (s_pp2 + s_t2 + SM);
    float inter2 = N - s_p2 - s_t2 + s_pt2;
    float denom2 = 2.0f * N - 2.0f * s_p2 + s_pp2 - s_t2;
    float rdice = 1.0f - (2.0f * inter2 + SM) / (denom2 + SM);

    float np4 = s_t2 + __shfl_xor(s_t2, 1);
    np4 += __shfl_xor(np4, 2);
    const float total = (float)(C_DIM * HW);  // 1048576
    float alpha = (total - np4) / total;

    float val = alpha * sum1 + (1.0f - alpha) * sum2
              + 2500.0f * (dice + rdice);

#pragma unroll
    for (int off = 32; off; off >>= 1) val += __shfl_down(val, off);
    if (p == 0) out[0] = val;
  }
}

// fallback second kernel (only used if ws lacks room for the counter)
__global__ __launch_bounds__(64) void loss_finalize(
    const float* __restrict__ ws, float* __restrict__ out) {
  const int p = threadIdx.x;
  float s[NSUMS] = {0.f, 0.f, 0.f, 0.f, 0.f, 0.f};
  for (int k = 0; k < K_CHUNKS; ++k) {
    const float* w = ws + (p * K_CHUNKS + k) * NSUMS;
#pragma unroll
    for (int q = 0; q < NSUMS; ++q) s[q] += w[q];
  }
  const float s_pt = s[0], s_pp = s[1], s_t = s[2], s_p = s[3];
  const float sum1 = s[4];
  const float sum2 = s[5] - s[4];
  const float N = (float)HW;
  const float SM = 1e-6f;
  float dice = 1.0f - (2.0f * s_pt + SM) / (s_pp + s_t + SM);
  float inter2 = N - s_p - s_t + s_pt;
  float denom2 = 2.0f * N - 2.0f * s_p + s_pp - s_t;
  float rdice = 1.0f - (2.0f * inter2 + SM) / (denom2 + SM);
  float np4 = s_t + __shfl_xor(s_t, 1);
  np4 += __shfl_xor(np4, 2);
  const float total = (float)(C_DIM * HW);
  float alpha = (total - np4) / total;
  float val = alpha * sum1 + (1.0f - alpha) * sum2 + 2500.0f * (dice + rdice);
#pragma unroll
  for (int off = 32; off; off >>= 1) val += __shfl_down(val, off);
  if (p == 0) out[0] = val;
}

extern "C" void kernel_launch(void* const* d_in, const int* in_sizes, int n_in,
                              void* d_out, int out_size, void* d_ws, size_t ws_size,
                              hipStream_t stream) {
  const float* pred = (const float*)d_in[0];
  const int* label = (const int*)d_in[1];
  float* out = (float*)d_out;
  float* ws = (float*)d_ws;  // partials: NBLOCKS*NSUMS*4 = 48 KiB (+4 counter)
  unsigned* counter = (unsigned*)((char*)d_ws + (size_t)NBLOCKS * NSUMS * 4);

  const int fuse = (ws_size >= (size_t)NBLOCKS * NSUMS * 4 + 4) ? 1 : 0;
  if (fuse) hipMemsetAsync(counter, 0, 4, stream);
  loss_main<<<NBLOCKS, 256, 0, stream>>>(pred, label, ws, counter, out, fuse);
  if (!fuse) loss_finalize<<<1, 64, 0, stream>>>(ws, out);
}